// Round 14
// baseline (220.231 us; speedup 1.0000x reference)
//
#include <hip/hip_runtime.h>

typedef __attribute__((ext_vector_type(8))) short short8;
typedef __attribute__((ext_vector_type(4))) float f32x4;
typedef __attribute__((ext_vector_type(4))) unsigned int u32x4;

#define MFMA(a,b,c) __builtin_amdgcn_mfma_f32_16x16x32_bf16((a),(b),(c),0,0,0)

__device__ __forceinline__ unsigned short f2bf(float f){
    unsigned u = __float_as_uint(f);
    u += 0x7FFFu + ((u >> 16) & 1u);   // RNE
    return (unsigned short)(u >> 16);
}
__device__ __forceinline__ unsigned pack2(float lo, float hi){
    return (unsigned)f2bf(lo) | ((unsigned)f2bf(hi) << 16);
}

// d_out: 33,554,432 f32 = Re(out[b,j]) at flat b*4096 + j.
// y1 intermediate: packed bf16 complex u32 (re|im<<16) at u32 slot b*4096 + r*64 + l.
// d_ws (>=2 MiB): fragment-ready bf16 weights (layouts as round 10).

// ---------------------------------------------------------------------------
__global__ __launch_bounds__(256) void k_prep(const float* __restrict__ w1,
                                              const float* __restrict__ w2,
                                              unsigned int* __restrict__ w1f,
                                              unsigned int* __restrict__ w2f){
    const int g = blockIdx.x * 256 + threadIdx.x;
    if (g < 65536) {
        const int lane = g & 63, mw = (g >> 6) & 3, kc = (g >> 8) & 1, c = (g >> 9) & 1, r = g >> 10;
        const int Lrow = lane >> 4, idx = lane & 15;
        const float* src = w1 + ((size_t)(r * 64 + mw * 16 + idx) * 64 + kc * 32 + Lrow * 8) * 2 + c;
        unsigned o[4];
        #pragma unroll
        for (int jp = 0; jp < 4; ++jp)
            o[jp] = pack2(src[jp * 4], src[jp * 4 + 2]);
        *(u32x4*)(w1f + (size_t)g * 4) = *(u32x4*)o;
    } else {
        const int h = g - 65536;
        const int lane = h & 63, mw = (h >> 6) & 3, kc = (h >> 8) & 3, l = h >> 10;
        const int Lrow = lane >> 4, idx = lane & 15;
        const float* src = w2 + ((size_t)(l * 64 + mw * 16 + idx) * 64 + kc * 16 + Lrow * 4) * 2;
        unsigned o[4];
        #pragma unroll
        for (int jp = 0; jp < 4; ++jp)
            o[jp] = pack2(src[jp * 2], -src[jp * 2 + 1]);   // (re, -im)
        *(u32x4*)(w2f + (size_t)h * 4) = *(u32x4*)o;
    }
}

// ---------------------------------------------------------------------------
// Stage 1 body (r10 configuration): y1[b, r*64+l] = sum_p w1[r,l,p] * x[b, p*64+r]
// Plain bid decode (bt=bid>>2, rc=bid&3), direct fragment stores.
// Instantiated twice with different launch bounds for within-probe A/B.
// ---------------------------------------------------------------------------
#define STAGE1_BODY                                                                                 \
    __shared__ unsigned int BF[8192];              /* 32 KB */                                      \
    const int tid = threadIdx.x;                                                                    \
    const int bt = blockIdx.x >> 2, rc = blockIdx.x & 3;                                            \
    const int b0 = bt * 16, r0 = rc * 16;                                                           \
    {                                                                                               \
        const int pe = tid >> 3;                                                                    \
        const int rq = (tid >> 1) & 3;                                                              \
        const int bh = tid & 1;                                                                     \
        const int kc = pe >> 4, gg = (pe >> 2) & 3, jp = pe & 3;                                    \
        const float* src = x + (size_t)(b0 + bh * 8) * 4096 + (pe * 2) * 64 + r0 + rq * 4;          \
        _Pragma("unroll")                                                                           \
        for (int itr = 0; itr < 8; ++itr) {                                                         \
            f32x4 v0 = *(const f32x4*)(src + (size_t)itr * 4096);                                   \
            f32x4 v1 = *(const f32x4*)(src + (size_t)itr * 4096 + 64);                              \
            const int b = bh * 8 + itr;                                                             \
            const int ROW = ((b ^ (b >> 3) ^ (gg << 1) ^ kc ^ (rq << 2)) & 15) | (gg << 4);         \
            const int base = kc * 256 + ROW * 4 + jp;                                               \
            _Pragma("unroll")                                                                       \
            for (int m = 0; m < 4; ++m)                                                             \
                BF[(rq * 4 + m) * 512 + base] = pack2(v0[m], v1[m]);                                \
        }                                                                                           \
    }                                                                                               \
    __syncthreads();                                                                                \
    const int lane = tid & 63, mw = tid >> 6;                                                       \
    const int Lrow = lane >> 4, idx = lane & 15;                                                    \
    const unsigned short* wbase = w1b + mw * 512 + lane * 8;                                        \
    _Pragma("unroll")                                                                               \
    for (int rr2 = 0; rr2 < 8; ++rr2) {                                                             \
        const int rA = rr2 * 2;                                                                     \
        f32x4 acc[2][2] = {};                                                                       \
        _Pragma("unroll")                                                                           \
        for (int kc = 0; kc < 2; ++kc) {                                                            \
            const int ROWr = ((idx ^ (idx >> 3) ^ (Lrow << 1) ^ kc ^ ((rr2 >> 1) << 2)) & 15) | (Lrow << 4); \
            short8 bA = *(const short8*)&BF[(rA + 0) * 512 + kc * 256 + ROWr * 4];                  \
            short8 bB = *(const short8*)&BF[(rA + 1) * 512 + kc * 256 + ROWr * 4];                  \
            _Pragma("unroll")                                                                       \
            for (int rp = 0; rp < 2; ++rp) {                                                        \
                const size_t wb = (size_t)(r0 + rA + rp) * 8192 + kc * 2048;                        \
                short8 a0 = *(const short8*)(wbase + wb);                                           \
                short8 a1 = *(const short8*)(wbase + wb + 4096);                                    \
                short8 bb = rp ? bB : bA;                                                           \
                acc[rp][0] = MFMA(a0, bb, acc[rp][0]);                                              \
                acc[rp][1] = MFMA(a1, bb, acc[rp][1]);                                              \
            }                                                                                       \
        }                                                                                           \
        _Pragma("unroll")                                                                           \
        for (int rp = 0; rp < 2; ++rp) {                                                            \
            u32x4 ov;                                                                               \
            _Pragma("unroll")                                                                       \
            for (int reg = 0; reg < 4; ++reg)                                                       \
                ov[reg] = pack2(acc[rp][0][reg], acc[rp][1][reg]);                                  \
            *(u32x4*)(y1 + (size_t)(b0 + idx) * 4096 + (size_t)(r0 + rA + rp) * 64 + mw * 16 + Lrow * 4) = ov; \
        }                                                                                           \
    }

__global__ __launch_bounds__(256) void k_stage1fA(const float* __restrict__ x,
                                                  const unsigned short* __restrict__ w1b,
                                                  unsigned int* __restrict__ y1){
    STAGE1_BODY
}

__global__ __launch_bounds__(256, 2) void k_stage1fB(const float* __restrict__ x,
                                                     const unsigned short* __restrict__ w1b,
                                                     unsigned int* __restrict__ y1){
    STAGE1_BODY
}

// ---------------------------------------------------------------------------
// Stage 2 (fast, real output only, in place over d_out) — r11/r13 version.
// ---------------------------------------------------------------------------
__global__ __launch_bounds__(256) void k_stage2f(const unsigned int* __restrict__ y1,
                                                 const unsigned short* __restrict__ w2b,
                                                 float* __restrict__ outf){
    __shared__ unsigned int Y[16384];              // 64 KB
    const int tid = threadIdx.x;
    const int bid = blockIdx.x;
    const int inner = (bid >> 3) & 1;
    const int pp = (bid >> 4) * 8 + (bid & 7);
    const int bt = pp >> 1, lc = (pp & 1) * 2 + inner;
    const int b0 = bt * 16, l0 = lc * 16;
    const int lane = tid & 63, mw = tid >> 6;
    const int Lrow = lane >> 4, idx = lane & 15;

    {   // ---- stage y1 l-slice -> LDS (all global reads precede the barrier) ----
        const int r_lo = lane >> 2, cg = lane & 3;
        const int r = mw * 16 + r_lo;
        const unsigned int* src = y1 + (size_t)b0 * 4096 + r * 64 + l0 + cg * 4;
        #pragma unroll
        for (int b = 0; b < 16; ++b) {
            u32x4 v = *(const u32x4*)(src + (size_t)b * 4096);
            const int rsw = r ^ (b << 2) ^ ((cg & 1) << 4);
            #pragma unroll
            for (int q = 0; q < 4; ++q)
                Y[(cg * 4 + q) * 1024 + b * 64 + rsw] = v[q];
        }
    }
    __syncthreads();

    const unsigned short* wbase = w2b + mw * 512 + lane * 8;
    float vRe[4][16];
    #pragma unroll
    for (int li = 0; li < 16; ++li) {
        const int l = l0 + li;
        const int g1 = ((li >> 2) & 1) << 4;
        f32x4 aRe = {};
        #pragma unroll
        for (int kc = 0; kc < 4; ++kc) {
            const int rb = kc * 16 + Lrow * 4;
            const int rsw = rb ^ (idx << 2) ^ g1;
            short8 bfrag = *(const short8*)&Y[li * 1024 + idx * 64 + rsw];
            short8 are   = *(const short8*)(wbase + (size_t)l * 8192 + kc * 2048);
            aRe = MFMA(are, bfrag, aRe);
        }
        #pragma unroll
        for (int reg = 0; reg < 4; ++reg)
            vRe[reg][li] = aRe[reg];
    }

    __syncthreads();
    float* Yf = (float*)Y;
    #pragma unroll
    for (int reg = 0; reg < 4; ++reg) {
        const int s = mw * 16 + Lrow * 4 + reg;
        #pragma unroll
        for (int q = 0; q < 4; ++q) {
            f32x4 v = { vRe[reg][q*4+0], vRe[reg][q*4+1], vRe[reg][q*4+2], vRe[reg][q*4+3] };
            *(f32x4*)&Yf[idx * 1024 + s * 16 + (((q ^ (idx & 3)) << 2))] = v;
        }
    }
    __syncthreads();

    {   // ---- coalesced store ----
        const int s2 = tid >> 2, c4 = tid & 3;
        #pragma unroll
        for (int i = 0; i < 16; ++i) {
            f32x4 v = *(const f32x4*)&Yf[i * 1024 + s2 * 16 + (((c4 ^ (i & 3)) << 2))];
            *(f32x4*)(outf + (size_t)(b0 + i) * 4096 + s2 * 64 + l0 + c4 * 4) = v;
        }
    }
}

// ===========================================================================
// Fallback path (round-9 verified kernels) — used only if ws_size < 2 MiB.
// ===========================================================================
__global__ __launch_bounds__(256) void k_stage1(const float* __restrict__ x,
                                                const float* __restrict__ w1,
                                                unsigned int* __restrict__ y1){
    __shared__ unsigned int BF[8192];
    const int tid = threadIdx.x;
    const int bt = blockIdx.x >> 2, rc = blockIdx.x & 3;
    const int b0 = bt * 16, r0 = rc * 16;
    {
        const int pe = tid >> 3;
        const int rq = (tid >> 1) & 3;
        const int bh = tid & 1;
        const int kc = pe >> 4, gg = (pe >> 2) & 3, jp = pe & 3;
        const float* src = x + (size_t)(b0 + bh * 8) * 4096 + (pe * 2) * 64 + r0 + rq * 4;
        #pragma unroll
        for (int itr = 0; itr < 8; ++itr) {
            f32x4 v0 = *(const f32x4*)(src + (size_t)itr * 4096);
            f32x4 v1 = *(const f32x4*)(src + (size_t)itr * 4096 + 64);
            const int b = bh * 8 + itr;
            const int ROW = ((b ^ (b >> 3) ^ (gg << 1) ^ kc ^ (rq << 2)) & 15) | (gg << 4);
            const int base = kc * 256 + ROW * 4 + jp;
            #pragma unroll
            for (int m = 0; m < 4; ++m)
                BF[(rq * 4 + m) * 512 + base] = pack2(v0[m], v1[m]);
        }
    }
    __syncthreads();
    const int lane = tid & 63, mw = tid >> 6;
    const int Lrow = lane >> 4, idx = lane & 15;
    #pragma unroll
    for (int rr2 = 0; rr2 < 8; ++rr2) {
        const int rA = rr2 * 2;
        f32x4 acc[2][2] = {};
        #pragma unroll
        for (int kc = 0; kc < 2; ++kc) {
            const int ROWr = ((idx ^ (idx >> 3) ^ (Lrow << 1) ^ kc ^ ((rr2 >> 1) << 2)) & 15) | (Lrow << 4);
            short8 bA = *(const short8*)&BF[(rA + 0) * 512 + kc * 256 + ROWr * 4];
            short8 bB = *(const short8*)&BF[(rA + 1) * 512 + kc * 256 + ROWr * 4];
            #pragma unroll
            for (int rp = 0; rp < 2; ++rp) {
                const int r = r0 + rA + rp;
                const float* wp = w1 + (((size_t)r * 64 + mw * 16 + idx) * 64 + kc * 32 + Lrow * 8) * 2;
                f32x4 q0 = *(const f32x4*)(wp);
                f32x4 q1 = *(const f32x4*)(wp + 4);
                f32x4 q2 = *(const f32x4*)(wp + 8);
                f32x4 q3 = *(const f32x4*)(wp + 12);
                short8 a0, a1;
                unsigned* p0 = (unsigned*)&a0; unsigned* p1 = (unsigned*)&a1;
                p0[0] = pack2(q0[0], q0[2]); p0[1] = pack2(q1[0], q1[2]);
                p0[2] = pack2(q2[0], q2[2]); p0[3] = pack2(q3[0], q3[2]);
                p1[0] = pack2(q0[1], q0[3]); p1[1] = pack2(q1[1], q1[3]);
                p1[2] = pack2(q2[1], q2[3]); p1[3] = pack2(q3[1], q3[3]);
                short8 bb = rp ? bB : bA;
                acc[rp][0] = MFMA(a0, bb, acc[rp][0]);
                acc[rp][1] = MFMA(a1, bb, acc[rp][1]);
            }
        }
        #pragma unroll
        for (int rp = 0; rp < 2; ++rp) {
            u32x4 ov;
            #pragma unroll
            for (int reg = 0; reg < 4; ++reg)
                ov[reg] = pack2(acc[rp][0][reg], acc[rp][1][reg]);
            *(u32x4*)(y1 + (size_t)(b0 + idx) * 4096 + (size_t)(r0 + rA + rp) * 64 + mw * 16 + Lrow * 4) = ov;
        }
    }
}

__global__ __launch_bounds__(256) void k_stage2(const unsigned int* __restrict__ y1,
                                                const float* __restrict__ w2,
                                                float* __restrict__ outf){
    __shared__ unsigned int Y[16384];
    const int tid = threadIdx.x;
    const int bt = blockIdx.x >> 2, lc = blockIdx.x & 3;
    const int b0 = bt * 16, l0 = lc * 16;
    const int lane = tid & 63, mw = tid >> 6;
    const int Lrow = lane >> 4, idx = lane & 15;
    {
        const int r_lo = lane >> 2, cg = lane & 3;
        const int r = mw * 16 + r_lo;
        const unsigned int* src = y1 + (size_t)b0 * 4096 + r * 64 + l0 + cg * 4;
        #pragma unroll
        for (int b = 0; b < 16; ++b) {
            u32x4 v = *(const u32x4*)(src + (size_t)b * 4096);
            const int rsw = r ^ (b << 2) ^ ((cg & 1) << 4);
            #pragma unroll
            for (int q = 0; q < 4; ++q)
                Y[(cg * 4 + q) * 1024 + b * 64 + rsw] = v[q];
        }
    }
    __syncthreads();
    float vRe[4][16];
    #pragma unroll
    for (int li = 0; li < 16; ++li) {
        const int l = l0 + li;
        const float* wp0 = w2 + ((size_t)l * 64 + mw * 16 + idx) * 128;
        const int g1 = ((li >> 2) & 1) << 4;
        f32x4 aRe = {};
        #pragma unroll
        for (int kc = 0; kc < 4; ++kc) {
            const int rb = kc * 16 + Lrow * 4;
            const int rsw = rb ^ (idx << 2) ^ g1;
            short8 bfrag = *(const short8*)&Y[li * 1024 + idx * 64 + rsw];
            const float* wp = wp0 + rb * 2;
            f32x4 u  = *(const f32x4*)wp;
            f32x4 vv = *(const f32x4*)(wp + 4);
            short8 are;
            unsigned* pr = (unsigned*)&are;
            pr[0] = pack2(u[0], -u[1]);   pr[1] = pack2(u[2], -u[3]);
            pr[2] = pack2(vv[0], -vv[1]); pr[3] = pack2(vv[2], -vv[3]);
            aRe = MFMA(are, bfrag, aRe);
        }
        #pragma unroll
        for (int reg = 0; reg < 4; ++reg)
            vRe[reg][li] = aRe[reg];
    }
    #pragma unroll
    for (int reg = 0; reg < 4; ++reg) {
        float* dst = outf + (size_t)(b0 + idx) * 4096 + (size_t)(mw * 16 + Lrow * 4 + reg) * 64 + l0;
        #pragma unroll
        for (int h = 0; h < 4; ++h) {
            f32x4 wv;
            wv[0] = vRe[reg][h*4+0]; wv[1] = vRe[reg][h*4+1];
            wv[2] = vRe[reg][h*4+2]; wv[3] = vRe[reg][h*4+3];
            *(f32x4*)(dst + h * 4) = wv;
        }
    }
}

extern "C" void kernel_launch(void* const* d_in, const int* in_sizes, int n_in,
                              void* d_out, int out_size, void* d_ws, size_t ws_size,
                              hipStream_t stream) {
    const float* x  = (const float*)d_in[0];
    const float* w1 = (const float*)d_in[1];
    const float* w2 = (const float*)d_in[2];
    unsigned int* y1 = (unsigned int*)d_out;
    float* outf = (float*)d_out;

    if (ws_size >= (size_t)2 * 1024 * 1024) {
        unsigned int* w1f = (unsigned int*)d_ws;           // 1 MiB
        unsigned int* w2f = w1f + 262144;                  // 1 MiB
        k_prep    <<<dim3(512),  dim3(256), 0, stream>>>(w1, w2, w1f, w2f);
        // Within-probe A/B: both variants write the identical y1 bit-pattern.
        k_stage1fA<<<dim3(2048), dim3(256), 0, stream>>>(x, (const unsigned short*)w1f, y1);
        k_stage1fB<<<dim3(2048), dim3(256), 0, stream>>>(x, (const unsigned short*)w1f, y1);
        k_stage2f <<<dim3(2048), dim3(256), 0, stream>>>(y1, (const unsigned short*)w2f, outf);
    } else {
        k_stage1<<<dim3(2048), dim3(256), 0, stream>>>(x, w1, y1);
        k_stage2<<<dim3(2048), dim3(256), 0, stream>>>(y1, w2, outf);
    }
}

// Round 15
// 190.561 us; speedup vs baseline: 1.1557x; 1.1557x over previous
//
#include <hip/hip_runtime.h>

typedef __attribute__((ext_vector_type(8))) short short8;
typedef __attribute__((ext_vector_type(4))) float f32x4;
typedef __attribute__((ext_vector_type(4))) unsigned int u32x4;

#define MFMA(a,b,c) __builtin_amdgcn_mfma_f32_16x16x32_bf16((a),(b),(c),0,0,0)

__device__ __forceinline__ unsigned short f2bf(float f){
    unsigned u = __float_as_uint(f);
    u += 0x7FFFu + ((u >> 16) & 1u);   // RNE
    return (unsigned short)(u >> 16);
}
__device__ __forceinline__ unsigned pack2(float lo, float hi){
    return (unsigned)f2bf(lo) | ((unsigned)f2bf(hi) << 16);
}

// d_out: 33,554,432 f32 = Re(out[b,j]) at flat b*4096 + j.
// d_ws (>=2 MiB): fragment-ready bf16 weights (layouts unchanged since r10):
//  w1f row g = (((r*2 + c)*2 + kc)*4 + lq)*512 : elem(lane,j) = w1[r][lq*16+(lane&15)][kc*32+(lane>>4)*8+j].c
//  w2f row h = ((l*4 + kc2)*4 + mt)*512       : elem(lane,j) = (j&1 ? -im : re) w2[l][mt*16+(lane&15)][kc2*16+(lane>>4)*4+(j>>1)]

// ---------------------------------------------------------------------------
__global__ __launch_bounds__(256) void k_prep(const float* __restrict__ w1,
                                              const float* __restrict__ w2,
                                              unsigned int* __restrict__ w1f,
                                              unsigned int* __restrict__ w2f){
    const int g = blockIdx.x * 256 + threadIdx.x;
    if (g < 65536) {
        const int lane = g & 63, mw = (g >> 6) & 3, kc = (g >> 8) & 1, c = (g >> 9) & 1, r = g >> 10;
        const int Lrow = lane >> 4, idx = lane & 15;
        const float* src = w1 + ((size_t)(r * 64 + mw * 16 + idx) * 64 + kc * 32 + Lrow * 8) * 2 + c;
        unsigned o[4];
        #pragma unroll
        for (int jp = 0; jp < 4; ++jp)
            o[jp] = pack2(src[jp * 4], src[jp * 4 + 2]);
        *(u32x4*)(w1f + (size_t)g * 4) = *(u32x4*)o;
    } else {
        const int h = g - 65536;
        const int lane = h & 63, mw = (h >> 6) & 3, kc = (h >> 8) & 3, l = h >> 10;
        const int Lrow = lane >> 4, idx = lane & 15;
        const float* src = w2 + ((size_t)(l * 64 + mw * 16 + idx) * 64 + kc * 16 + Lrow * 4) * 2;
        unsigned o[4];
        #pragma unroll
        for (int jp = 0; jp < 4; ++jp)
            o[jp] = pack2(src[jp * 2], -src[jp * 2 + 1]);   // (re, -im)
        *(u32x4*)(w2f + (size_t)h * 4) = *(u32x4*)o;
    }
}

// ---------------------------------------------------------------------------
// Fused kernel: block = 8 batches (b0..b0+7), 512 threads = 8 waves.
// Per l-chunk (16 l): stage-1 (y1 chunk in LDS) -> stage-2 -> coalesced flush.
// y1 never touches HBM.
// ---------------------------------------------------------------------------
__global__ __launch_bounds__(512, 2) void k_fused(const float* __restrict__ x,
                                                  const unsigned short* __restrict__ w1b,
                                                  const unsigned short* __restrict__ w2b,
                                                  float* __restrict__ outf){
    __shared__ unsigned short XF[32768];   // 64 KB: [b(8)][kc(2)][Lp(4)][rs(64)][j(8)] bf16
    __shared__ unsigned int  Y1C[8192];    // 32 KB: [li(16)][b(8)][rs2(64)] packed complex u32
    __shared__ float         OUTC[8192];   // 32 KB: [b(8)][s(64)][li'(16)] f32
    const int tid = threadIdx.x;
    const int w = tid >> 6, lane = tid & 63;
    const int idx = lane & 15, Lrow = lane >> 4;
    const int b0 = blockIdx.x * 8;
    const int bq = idx & 7;

    // ---- phase 0: stage x -> XF (fragment-ready, XOR-swizzled rs) ----
    {
        const int b = w;                                   // wave w stages batch row w
        const float* src = x + (size_t)(b0 + b) * 4096 + lane * 4;
        f32x4 xv[16];
        #pragma unroll
        for (int k = 0; k < 16; ++k)
            xv[k] = *(const f32x4*)(src + k * 256);        // coalesced, 16-deep MLP
        #pragma unroll
        for (int k = 0; k < 16; ++k) {
            const int c0 = k * 256 + lane * 4;             // flat col = p*64 + r
            const int p = c0 >> 6, r0 = c0 & 63;           // p const within the 4 (r0 4-aligned)
            const int kc = p >> 5, Lp = (p >> 3) & 3, j = p & 7;
            const int SWX = (b ^ (Lp << 1)) & 7;
            const int base = r0 ^ (SWX & 4);
            const int rot = SWX & 3;
            unsigned short* dst = &XF[(((b * 2 + kc) * 4 + Lp) * 64 + base) * 8 + j];
            #pragma unroll
            for (int m = 0; m < 4; ++m)
                dst[m * 8] = f2bf(xv[k][m ^ rot]);         // slot m holds r = base+m (value reordered)
        }
    }
    __syncthreads();

    for (int lc = 0; lc < 4; ++lc) {
        // ---- P1: stage-1 — y1c[li, b, r] for all 64 r (wave w: r = w*8..w*8+7) ----
        {
            const int SWX = (bq ^ (Lrow << 1)) & 7;
            const unsigned short* wb = w1b + lane * 8;
            #pragma unroll
            for (int rr = 0; rr < 8; ++rr) {
                const int r = w * 8 + rr;
                short8 bb0 = *(const short8*)&XF[(((bq * 2 + 0) * 4 + Lrow) * 64 + (r ^ SWX)) * 8];
                short8 bb1 = *(const short8*)&XF[(((bq * 2 + 1) * 4 + Lrow) * 64 + (r ^ SWX)) * 8];
                short8 aRe0 = *(const short8*)(wb + (size_t)(((r * 2 + 0) * 2 + 0) * 4 + lc) * 512);
                short8 aRe1 = *(const short8*)(wb + (size_t)(((r * 2 + 0) * 2 + 1) * 4 + lc) * 512);
                short8 aIm0 = *(const short8*)(wb + (size_t)(((r * 2 + 1) * 2 + 0) * 4 + lc) * 512);
                short8 aIm1 = *(const short8*)(wb + (size_t)(((r * 2 + 1) * 2 + 1) * 4 + lc) * 512);
                f32x4 accRe = {}, accIm = {};
                accRe = MFMA(aRe0, bb0, accRe); accRe = MFMA(aRe1, bb1, accRe);
                accIm = MFMA(aIm0, bb0, accIm); accIm = MFMA(aIm1, bb1, accIm);
                if (idx < 8) {
                    #pragma unroll
                    for (int reg = 0; reg < 4; ++reg)
                        Y1C[(Lrow * 4 + reg) * 512 + idx * 64 + (r ^ (idx << 2))]
                            = pack2(accRe[reg], accIm[reg]);
                }
            }
        }
        __syncthreads();

        // ---- P2: stage-2 — out[b, s, l0+li] = sum over all (r,c); wave w: li = 2w, 2w+1 ----
        {
            const unsigned short* wb = w2b + lane * 8;
            #pragma unroll
            for (int lh = 0; lh < 2; ++lh) {
                const int li = w * 2 + lh;
                const int l = lc * 16 + li;
                f32x4 acc[4] = {};
                #pragma unroll
                for (int kc2 = 0; kc2 < 4; ++kc2) {
                    short8 bfrag = *(const short8*)&Y1C[li * 512 + bq * 64 +
                                                        ((kc2 * 16 + Lrow * 4) ^ (bq << 2))];
                    #pragma unroll
                    for (int mt = 0; mt < 4; ++mt) {
                        short8 a = *(const short8*)(wb + (size_t)((l * 4 + kc2) * 4 + mt) * 512);
                        acc[mt] = MFMA(a, bfrag, acc[mt]);
                    }
                }
                if (idx < 8) {
                    #pragma unroll
                    for (int mt = 0; mt < 4; ++mt)
                        #pragma unroll
                        for (int reg = 0; reg < 4; ++reg) {
                            const int s = mt * 16 + Lrow * 4 + reg;
                            const int lis = li ^ ((idx << 1) & 15) ^ ((s >> 3) & 1);
                            OUTC[(idx * 64 + s) * 16 + lis] = acc[mt][reg];
                        }
                }
            }
        }
        __syncthreads();

        // ---- P3: flush OUTC -> global (wave w = batch row w; 4 full 64-B lines/inst) ----
        {
            const int b = w;
            const int sg = Lrow, li = idx;
            float* dst = outf + (size_t)(b0 + b) * 4096 + lc * 16;
            #pragma unroll
            for (int i = 0; i < 16; ++i) {
                const int s = i * 4 + sg;
                const int lis = li ^ ((b << 1) & 15) ^ ((s >> 3) & 1);
                dst[s * 64 + li] = OUTC[(b * 64 + s) * 16 + lis];
            }
        }
        __syncthreads();
    }
}

// ===========================================================================
// Fallback path (round-9 verified kernels) — used only if ws_size < 2 MiB.
// y1 parked in d_out (packed bf16 complex), stage-2 in place.
// ===========================================================================
__global__ __launch_bounds__(256) void k_stage1(const float* __restrict__ x,
                                                const float* __restrict__ w1,
                                                unsigned int* __restrict__ y1){
    __shared__ unsigned int BF[8192];
    const int tid = threadIdx.x;
    const int bt = blockIdx.x >> 2, rc = blockIdx.x & 3;
    const int b0 = bt * 16, r0 = rc * 16;
    {
        const int pe = tid >> 3;
        const int rq = (tid >> 1) & 3;
        const int bh = tid & 1;
        const int kc = pe >> 4, gg = (pe >> 2) & 3, jp = pe & 3;
        const float* src = x + (size_t)(b0 + bh * 8) * 4096 + (pe * 2) * 64 + r0 + rq * 4;
        #pragma unroll
        for (int itr = 0; itr < 8; ++itr) {
            f32x4 v0 = *(const f32x4*)(src + (size_t)itr * 4096);
            f32x4 v1 = *(const f32x4*)(src + (size_t)itr * 4096 + 64);
            const int b = bh * 8 + itr;
            const int ROW = ((b ^ (b >> 3) ^ (gg << 1) ^ kc ^ (rq << 2)) & 15) | (gg << 4);
            const int base = kc * 256 + ROW * 4 + jp;
            #pragma unroll
            for (int m = 0; m < 4; ++m)
                BF[(rq * 4 + m) * 512 + base] = pack2(v0[m], v1[m]);
        }
    }
    __syncthreads();
    const int lane = tid & 63, mw = tid >> 6;
    const int Lrow = lane >> 4, idx = lane & 15;
    #pragma unroll
    for (int rr2 = 0; rr2 < 8; ++rr2) {
        const int rA = rr2 * 2;
        f32x4 acc[2][2] = {};
        #pragma unroll
        for (int kc = 0; kc < 2; ++kc) {
            const int ROWr = ((idx ^ (idx >> 3) ^ (Lrow << 1) ^ kc ^ ((rr2 >> 1) << 2)) & 15) | (Lrow << 4);
            short8 bA = *(const short8*)&BF[(rA + 0) * 512 + kc * 256 + ROWr * 4];
            short8 bB = *(const short8*)&BF[(rA + 1) * 512 + kc * 256 + ROWr * 4];
            #pragma unroll
            for (int rp = 0; rp < 2; ++rp) {
                const int r = r0 + rA + rp;
                const float* wp = w1 + (((size_t)r * 64 + mw * 16 + idx) * 64 + kc * 32 + Lrow * 8) * 2;
                f32x4 q0 = *(const f32x4*)(wp);
                f32x4 q1 = *(const f32x4*)(wp + 4);
                f32x4 q2 = *(const f32x4*)(wp + 8);
                f32x4 q3 = *(const f32x4*)(wp + 12);
                short8 a0, a1;
                unsigned* p0 = (unsigned*)&a0; unsigned* p1 = (unsigned*)&a1;
                p0[0] = pack2(q0[0], q0[2]); p0[1] = pack2(q1[0], q1[2]);
                p0[2] = pack2(q2[0], q2[2]); p0[3] = pack2(q3[0], q3[2]);
                p1[0] = pack2(q0[1], q0[3]); p1[1] = pack2(q1[1], q1[3]);
                p1[2] = pack2(q2[1], q2[3]); p1[3] = pack2(q3[1], q3[3]);
                short8 bb = rp ? bB : bA;
                acc[rp][0] = MFMA(a0, bb, acc[rp][0]);
                acc[rp][1] = MFMA(a1, bb, acc[rp][1]);
            }
        }
        #pragma unroll
        for (int rp = 0; rp < 2; ++rp) {
            u32x4 ov;
            #pragma unroll
            for (int reg = 0; reg < 4; ++reg)
                ov[reg] = pack2(acc[rp][0][reg], acc[rp][1][reg]);
            *(u32x4*)(y1 + (size_t)(b0 + idx) * 4096 + (size_t)(r0 + rA + rp) * 64 + mw * 16 + Lrow * 4) = ov;
        }
    }
}

__global__ __launch_bounds__(256) void k_stage2(const unsigned int* __restrict__ y1,
                                                const float* __restrict__ w2,
                                                float* __restrict__ outf){
    __shared__ unsigned int Y[16384];
    const int tid = threadIdx.x;
    const int bt = blockIdx.x >> 2, lc = blockIdx.x & 3;
    const int b0 = bt * 16, l0 = lc * 16;
    const int lane = tid & 63, mw = tid >> 6;
    const int Lrow = lane >> 4, idx = lane & 15;
    {
        const int r_lo = lane >> 2, cg = lane & 3;
        const int r = mw * 16 + r_lo;
        const unsigned int* src = y1 + (size_t)b0 * 4096 + r * 64 + l0 + cg * 4;
        #pragma unroll
        for (int b = 0; b < 16; ++b) {
            u32x4 v = *(const u32x4*)(src + (size_t)b * 4096);
            const int rsw = r ^ (b << 2) ^ ((cg & 1) << 4);
            #pragma unroll
            for (int q = 0; q < 4; ++q)
                Y[(cg * 4 + q) * 1024 + b * 64 + rsw] = v[q];
        }
    }
    __syncthreads();
    float vRe[4][16];
    #pragma unroll
    for (int li = 0; li < 16; ++li) {
        const int l = l0 + li;
        const float* wp0 = w2 + ((size_t)l * 64 + mw * 16 + idx) * 128;
        const int g1 = ((li >> 2) & 1) << 4;
        f32x4 aRe = {};
        #pragma unroll
        for (int kc = 0; kc < 4; ++kc) {
            const int rb = kc * 16 + Lrow * 4;
            const int rsw = rb ^ (idx << 2) ^ g1;
            short8 bfrag = *(const short8*)&Y[li * 1024 + idx * 64 + rsw];
            const float* wp = wp0 + rb * 2;
            f32x4 u  = *(const f32x4*)wp;
            f32x4 vv = *(const f32x4*)(wp + 4);
            short8 are;
            unsigned* pr = (unsigned*)&are;
            pr[0] = pack2(u[0], -u[1]);   pr[1] = pack2(u[2], -u[3]);
            pr[2] = pack2(vv[0], -vv[1]); pr[3] = pack2(vv[2], -vv[3]);
            aRe = MFMA(are, bfrag, aRe);
        }
        #pragma unroll
        for (int reg = 0; reg < 4; ++reg)
            vRe[reg][li] = aRe[reg];
    }
    #pragma unroll
    for (int reg = 0; reg < 4; ++reg) {
        float* dst = outf + (size_t)(b0 + idx) * 4096 + (size_t)(mw * 16 + Lrow * 4 + reg) * 64 + l0;
        #pragma unroll
        for (int h = 0; h < 4; ++h) {
            f32x4 wv;
            wv[0] = vRe[reg][h*4+0]; wv[1] = vRe[reg][h*4+1];
            wv[2] = vRe[reg][h*4+2]; wv[3] = vRe[reg][h*4+3];
            *(f32x4*)(dst + h * 4) = wv;
        }
    }
}

extern "C" void kernel_launch(void* const* d_in, const int* in_sizes, int n_in,
                              void* d_out, int out_size, void* d_ws, size_t ws_size,
                              hipStream_t stream) {
    const float* x  = (const float*)d_in[0];
    const float* w1 = (const float*)d_in[1];
    const float* w2 = (const float*)d_in[2];
    float* outf = (float*)d_out;

    if (ws_size >= (size_t)2 * 1024 * 1024) {
        unsigned int* w1f = (unsigned int*)d_ws;           // 1 MiB
        unsigned int* w2f = w1f + 262144;                  // 1 MiB
        k_prep <<<dim3(512),  dim3(256), 0, stream>>>(w1, w2, w1f, w2f);
        k_fused<<<dim3(1024), dim3(512), 0, stream>>>(x, (const unsigned short*)w1f,
                                                      (const unsigned short*)w2f, outf);
    } else {
        unsigned int* y1 = (unsigned int*)d_out;           // in-place intermediate
        k_stage1<<<dim3(2048), dim3(256), 0, stream>>>(x, w1, y1);
        k_stage2<<<dim3(2048), dim3(256), 0, stream>>>(y1, w2, outf);
    }
}

// Round 16
// 156.377 us; speedup vs baseline: 1.4083x; 1.2186x over previous
//
#include <hip/hip_runtime.h>

typedef __attribute__((ext_vector_type(8))) short short8;
typedef __attribute__((ext_vector_type(4))) float f32x4;
typedef __attribute__((ext_vector_type(4))) unsigned int u32x4;

#define MFMA(a,b,c) __builtin_amdgcn_mfma_f32_16x16x32_bf16((a),(b),(c),0,0,0)

__device__ __forceinline__ unsigned short f2bf(float f){
    unsigned u = __float_as_uint(f);
    u += 0x7FFFu + ((u >> 16) & 1u);   // RNE
    return (unsigned short)(u >> 16);
}
__device__ __forceinline__ unsigned pack2(float lo, float hi){
    return (unsigned)f2bf(lo) | ((unsigned)f2bf(hi) << 16);
}

// d_out: 33,554,432 f32 = Re(out[b,j]) at flat b*4096 + j.
// d_ws (>=2 MiB): fragment-ready bf16 weights (layouts unchanged since r10):
//  w1f row g = (((r*2 + c)*2 + kc)*4 + lq)*512 : elem(lane,j) = w1[r][lq*16+(lane&15)][kc*32+(lane>>4)*8+j].c
//  w2f row h = ((l*4 + kc2)*4 + mt)*512       : elem(lane,j) = (j&1 ? -im : re) w2[l][mt*16+(lane&15)][kc2*16+(lane>>4)*4+(j>>1)]

// ---------------------------------------------------------------------------
__global__ __launch_bounds__(256) void k_prep(const float* __restrict__ w1,
                                              const float* __restrict__ w2,
                                              unsigned int* __restrict__ w1f,
                                              unsigned int* __restrict__ w2f){
    const int g = blockIdx.x * 256 + threadIdx.x;
    if (g < 65536) {
        const int lane = g & 63, mw = (g >> 6) & 3, kc = (g >> 8) & 1, c = (g >> 9) & 1, r = g >> 10;
        const int Lrow = lane >> 4, idx = lane & 15;
        const float* src = w1 + ((size_t)(r * 64 + mw * 16 + idx) * 64 + kc * 32 + Lrow * 8) * 2 + c;
        unsigned o[4];
        #pragma unroll
        for (int jp = 0; jp < 4; ++jp)
            o[jp] = pack2(src[jp * 4], src[jp * 4 + 2]);
        *(u32x4*)(w1f + (size_t)g * 4) = *(u32x4*)o;
    } else {
        const int h = g - 65536;
        const int lane = h & 63, mw = (h >> 6) & 3, kc = (h >> 8) & 3, l = h >> 10;
        const int Lrow = lane >> 4, idx = lane & 15;
        const float* src = w2 + ((size_t)(l * 64 + mw * 16 + idx) * 64 + kc * 16 + Lrow * 4) * 2;
        unsigned o[4];
        #pragma unroll
        for (int jp = 0; jp < 4; ++jp)
            o[jp] = pack2(src[jp * 2], -src[jp * 2 + 1]);   // (re, -im)
        *(u32x4*)(w2f + (size_t)h * 4) = *(u32x4*)o;
    }
}

// ---------------------------------------------------------------------------
// Fused kernel: block = 8 batches, 512 threads = 8 waves. y1 stays in LDS.
// All LDS writes are b128 with bank-spread verified per 8-lane group.
// ---------------------------------------------------------------------------
__global__ __launch_bounds__(512, 2) void k_fused(const float* __restrict__ x,
                                                  const unsigned short* __restrict__ w1b,
                                                  const unsigned short* __restrict__ w2b,
                                                  float* __restrict__ outf){
    __shared__ unsigned int XF[16384];     // 64 KB: frag (b8,kc2,Lp4,r'64) x 4 u32
    __shared__ unsigned int Y1C[8192];     // 32 KB: [li16][b8][slot64] packed complex u32
    __shared__ float        OUTC[8192];    // 32 KB: [b8][s64][li'16] f32
    const int tid = threadIdx.x;
    const int w = tid >> 6, lane = tid & 63;
    const int idx = lane & 15, Lrow = lane >> 4;
    const int b0 = blockIdx.x * 8;
    const int bq = idx & 7;

    // ---- phase 0: x -> XF fragments. Lane r=lane assembles its own fragment:
    //      8 coalesced j-strided loads, one b128 LDS write at r^SWX (conflict-free).
    {
        const int b = w;
        const float* xb = x + (size_t)(b0 + b) * 4096;
        #pragma unroll
        for (int kc = 0; kc < 2; ++kc)
            #pragma unroll
            for (int Lp = 0; Lp < 4; ++Lp) {
                float xj[8];
                #pragma unroll
                for (int j = 0; j < 8; ++j)
                    xj[j] = xb[(kc * 32 + Lp * 8 + j) * 64 + lane];
                u32x4 ov;
                #pragma unroll
                for (int jp = 0; jp < 4; ++jp)
                    ov[jp] = pack2(xj[2 * jp], xj[2 * jp + 1]);
                const int SWX = (b ^ (Lp << 1)) & 7;
                *(u32x4*)&XF[(((b * 2 + kc) * 4 + Lp) * 64 + (lane ^ SWX)) * 4] = ov;
            }
    }
    __syncthreads();

    for (int lc = 0; lc < 4; ++lc) {
        // ---- P1: stage-1 (wave w: r = w*8..w*8+7, in two 4-r groups, b128 Y1C writes) ----
        {
            const int SWX = (bq ^ (Lrow << 1)) & 7;
            const unsigned short* wb = w1b + lane * 8;
            #pragma unroll
            for (int rrg = 0; rrg < 2; ++rrg) {
                u32x4 ov[4];
                #pragma unroll
                for (int rr4 = 0; rr4 < 4; ++rr4) {
                    const int r = w * 8 + rrg * 4 + rr4;
                    short8 bb0 = *(const short8*)&XF[(((bq * 2 + 0) * 4 + Lrow) * 64 + (r ^ SWX)) * 4];
                    short8 bb1 = *(const short8*)&XF[(((bq * 2 + 1) * 4 + Lrow) * 64 + (r ^ SWX)) * 4];
                    short8 aRe0 = *(const short8*)(wb + (size_t)(((r * 2 + 0) * 2 + 0) * 4 + lc) * 512);
                    short8 aRe1 = *(const short8*)(wb + (size_t)(((r * 2 + 0) * 2 + 1) * 4 + lc) * 512);
                    short8 aIm0 = *(const short8*)(wb + (size_t)(((r * 2 + 1) * 2 + 0) * 4 + lc) * 512);
                    short8 aIm1 = *(const short8*)(wb + (size_t)(((r * 2 + 1) * 2 + 1) * 4 + lc) * 512);
                    f32x4 accRe = {}, accIm = {};
                    accRe = MFMA(aRe0, bb0, accRe); accRe = MFMA(aRe1, bb1, accRe);
                    accIm = MFMA(aIm0, bb0, accIm); accIm = MFMA(aIm1, bb1, accIm);
                    #pragma unroll
                    for (int reg = 0; reg < 4; ++reg)
                        ov[reg][rr4] = pack2(accRe[reg], accIm[reg]);
                }
                if (idx < 8) {
                    const int slot = (w * 8 + rrg * 4) ^ ((bq ^ Lrow) << 2);
                    #pragma unroll
                    for (int reg = 0; reg < 4; ++reg) {
                        const int li = Lrow * 4 + reg;
                        *(u32x4*)&Y1C[li * 512 + bq * 64 + slot] = ov[reg];
                    }
                }
            }
        }
        __syncthreads();

        // ---- P2: stage-2 (wave w: li = 2w, 2w+1; slot function matches P1 writer) ----
        {
            const unsigned short* wb = w2b + lane * 8;
            #pragma unroll
            for (int lh = 0; lh < 2; ++lh) {
                const int li = w * 2 + lh;
                const int l = lc * 16 + li;
                const int tsw = li >> 2;
                f32x4 acc[4] = {};
                #pragma unroll
                for (int kc2 = 0; kc2 < 4; ++kc2) {
                    const int rbase = kc2 * 16 + Lrow * 4;
                    const int slot = rbase ^ ((bq ^ tsw) << 2);
                    short8 bfrag = *(const short8*)&Y1C[li * 512 + bq * 64 + slot];
                    #pragma unroll
                    for (int mt = 0; mt < 4; ++mt) {
                        short8 a = *(const short8*)(wb + (size_t)((l * 4 + kc2) * 4 + mt) * 512);
                        acc[mt] = MFMA(a, bfrag, acc[mt]);
                    }
                }
                if (idx < 8) {
                    #pragma unroll
                    for (int mt = 0; mt < 4; ++mt)
                        #pragma unroll
                        for (int reg = 0; reg < 4; ++reg) {
                            const int s = mt * 16 + Lrow * 4 + reg;
                            const int lis = li ^ ((idx << 1) & 15) ^ ((s >> 3) & 1);
                            OUTC[(idx * 64 + s) * 16 + lis] = acc[mt][reg];
                        }
                }
            }
        }
        __syncthreads();

        // ---- P3: flush OUTC -> global (wave w = batch row w) ----
        {
            const int b = w;
            const int sg = Lrow, li = idx;
            float* dst = outf + (size_t)(b0 + b) * 4096 + lc * 16;
            #pragma unroll
            for (int i = 0; i < 16; ++i) {
                const int s = i * 4 + sg;
                const int lis = li ^ ((b << 1) & 15) ^ ((s >> 3) & 1);
                dst[s * 64 + li] = OUTC[(b * 64 + s) * 16 + lis];
            }
        }
        __syncthreads();
    }
}

// ===========================================================================
// Fallback path (round-9 verified kernels) — used only if ws_size < 2 MiB.
// y1 parked in d_out (packed bf16 complex), stage-2 in place.
// ===========================================================================
__global__ __launch_bounds__(256) void k_stage1(const float* __restrict__ x,
                                                const float* __restrict__ w1,
                                                unsigned int* __restrict__ y1){
    __shared__ unsigned int BF[8192];
    const int tid = threadIdx.x;
    const int bt = blockIdx.x >> 2, rc = blockIdx.x & 3;
    const int b0 = bt * 16, r0 = rc * 16;
    {
        const int pe = tid >> 3;
        const int rq = (tid >> 1) & 3;
        const int bh = tid & 1;
        const int kc = pe >> 4, gg = (pe >> 2) & 3, jp = pe & 3;
        const float* src = x + (size_t)(b0 + bh * 8) * 4096 + (pe * 2) * 64 + r0 + rq * 4;
        #pragma unroll
        for (int itr = 0; itr < 8; ++itr) {
            f32x4 v0 = *(const f32x4*)(src + (size_t)itr * 4096);
            f32x4 v1 = *(const f32x4*)(src + (size_t)itr * 4096 + 64);
            const int b = bh * 8 + itr;
            const int ROW = ((b ^ (b >> 3) ^ (gg << 1) ^ kc ^ (rq << 2)) & 15) | (gg << 4);
            const int base = kc * 256 + ROW * 4 + jp;
            #pragma unroll
            for (int m = 0; m < 4; ++m)
                BF[(rq * 4 + m) * 512 + base] = pack2(v0[m], v1[m]);
        }
    }
    __syncthreads();
    const int lane = tid & 63, mw = tid >> 6;
    const int Lrow = lane >> 4, idx = lane & 15;
    #pragma unroll
    for (int rr2 = 0; rr2 < 8; ++rr2) {
        const int rA = rr2 * 2;
        f32x4 acc[2][2] = {};
        #pragma unroll
        for (int kc = 0; kc < 2; ++kc) {
            const int ROWr = ((idx ^ (idx >> 3) ^ (Lrow << 1) ^ kc ^ ((rr2 >> 1) << 2)) & 15) | (Lrow << 4);
            short8 bA = *(const short8*)&BF[(rA + 0) * 512 + kc * 256 + ROWr * 4];
            short8 bB = *(const short8*)&BF[(rA + 1) * 512 + kc * 256 + ROWr * 4];
            #pragma unroll
            for (int rp = 0; rp < 2; ++rp) {
                const int r = r0 + rA + rp;
                const float* wp = w1 + (((size_t)r * 64 + mw * 16 + idx) * 64 + kc * 32 + Lrow * 8) * 2;
                f32x4 q0 = *(const f32x4*)(wp);
                f32x4 q1 = *(const f32x4*)(wp + 4);
                f32x4 q2 = *(const f32x4*)(wp + 8);
                f32x4 q3 = *(const f32x4*)(wp + 12);
                short8 a0, a1;
                unsigned* p0 = (unsigned*)&a0; unsigned* p1 = (unsigned*)&a1;
                p0[0] = pack2(q0[0], q0[2]); p0[1] = pack2(q1[0], q1[2]);
                p0[2] = pack2(q2[0], q2[2]); p0[3] = pack2(q3[0], q3[2]);
                p1[0] = pack2(q0[1], q0[3]); p1[1] = pack2(q1[1], q1[3]);
                p1[2] = pack2(q2[1], q2[3]); p1[3] = pack2(q3[1], q3[3]);
                short8 bb = rp ? bB : bA;
                acc[rp][0] = MFMA(a0, bb, acc[rp][0]);
                acc[rp][1] = MFMA(a1, bb, acc[rp][1]);
            }
        }
        #pragma unroll
        for (int rp = 0; rp < 2; ++rp) {
            u32x4 ov;
            #pragma unroll
            for (int reg = 0; reg < 4; ++reg)
                ov[reg] = pack2(acc[rp][0][reg], acc[rp][1][reg]);
            *(u32x4*)(y1 + (size_t)(b0 + idx) * 4096 + (size_t)(r0 + rA + rp) * 64 + mw * 16 + Lrow * 4) = ov;
        }
    }
}

__global__ __launch_bounds__(256) void k_stage2(const unsigned int* __restrict__ y1,
                                                const float* __restrict__ w2,
                                                float* __restrict__ outf){
    __shared__ unsigned int Y[16384];
    const int tid = threadIdx.x;
    const int bt = blockIdx.x >> 2, lc = blockIdx.x & 3;
    const int b0 = bt * 16, l0 = lc * 16;
    const int lane = tid & 63, mw = tid >> 6;
    const int Lrow = lane >> 4, idx = lane & 15;
    {
        const int r_lo = lane >> 2, cg = lane & 3;
        const int r = mw * 16 + r_lo;
        const unsigned int* src = y1 + (size_t)b0 * 4096 + r * 64 + l0 + cg * 4;
        #pragma unroll
        for (int b = 0; b < 16; ++b) {
            u32x4 v = *(const u32x4*)(src + (size_t)b * 4096);
            const int rsw = r ^ (b << 2) ^ ((cg & 1) << 4);
            #pragma unroll
            for (int q = 0; q < 4; ++q)
                Y[(cg * 4 + q) * 1024 + b * 64 + rsw] = v[q];
        }
    }
    __syncthreads();
    float vRe[4][16];
    #pragma unroll
    for (int li = 0; li < 16; ++li) {
        const int l = l0 + li;
        const float* wp0 = w2 + ((size_t)l * 64 + mw * 16 + idx) * 128;
        const int g1 = ((li >> 2) & 1) << 4;
        f32x4 aRe = {};
        #pragma unroll
        for (int kc = 0; kc < 4; ++kc) {
            const int rb = kc * 16 + Lrow * 4;
            const int rsw = rb ^ (idx << 2) ^ g1;
            short8 bfrag = *(const short8*)&Y[li * 1024 + idx * 64 + rsw];
            const float* wp = wp0 + rb * 2;
            f32x4 u  = *(const f32x4*)wp;
            f32x4 vv = *(const f32x4*)(wp + 4);
            short8 are;
            unsigned* pr = (unsigned*)&are;
            pr[0] = pack2(u[0], -u[1]);   pr[1] = pack2(u[2], -u[3]);
            pr[2] = pack2(vv[0], -vv[1]); pr[3] = pack2(vv[2], -vv[3]);
            aRe = MFMA(are, bfrag, aRe);
        }
        #pragma unroll
        for (int reg = 0; reg < 4; ++reg)
            vRe[reg][li] = aRe[reg];
    }
    #pragma unroll
    for (int reg = 0; reg < 4; ++reg) {
        float* dst = outf + (size_t)(b0 + idx) * 4096 + (size_t)(mw * 16 + Lrow * 4 + reg) * 64 + l0;
        #pragma unroll
        for (int h = 0; h < 4; ++h) {
            f32x4 wv;
            wv[0] = vRe[reg][h*4+0]; wv[1] = vRe[reg][h*4+1];
            wv[2] = vRe[reg][h*4+2]; wv[3] = vRe[reg][h*4+3];
            *(f32x4*)(dst + h * 4) = wv;
        }
    }
}

extern "C" void kernel_launch(void* const* d_in, const int* in_sizes, int n_in,
                              void* d_out, int out_size, void* d_ws, size_t ws_size,
                              hipStream_t stream) {
    const float* x  = (const float*)d_in[0];
    const float* w1 = (const float*)d_in[1];
    const float* w2 = (const float*)d_in[2];
    float* outf = (float*)d_out;

    if (ws_size >= (size_t)2 * 1024 * 1024) {
        unsigned int* w1f = (unsigned int*)d_ws;           // 1 MiB
        unsigned int* w2f = w1f + 262144;                  // 1 MiB
        k_prep <<<dim3(512),  dim3(256), 0, stream>>>(w1, w2, w1f, w2f);
        k_fused<<<dim3(1024), dim3(512), 0, stream>>>(x, (const unsigned short*)w1f,
                                                      (const unsigned short*)w2f, outf);
    } else {
        unsigned int* y1 = (unsigned int*)d_out;           // in-place intermediate
        k_stage1<<<dim3(2048), dim3(256), 0, stream>>>(x, w1, y1);
        k_stage2<<<dim3(2048), dim3(256), 0, stream>>>(y1, w2, outf);
    }
}

// Round 17
// 138.498 us; speedup vs baseline: 1.5901x; 1.1291x over previous
//
#include <hip/hip_runtime.h>

typedef __attribute__((ext_vector_type(8))) short short8;
typedef __attribute__((ext_vector_type(4))) float f32x4;
typedef __attribute__((ext_vector_type(4))) unsigned int u32x4;

#define MFMA(a,b,c) __builtin_amdgcn_mfma_f32_16x16x32_bf16((a),(b),(c),0,0,0)

__device__ __forceinline__ unsigned short f2bf(float f){
    unsigned u = __float_as_uint(f);
    u += 0x7FFFu + ((u >> 16) & 1u);   // RNE
    return (unsigned short)(u >> 16);
}
__device__ __forceinline__ unsigned pack2(float lo, float hi){
    return (unsigned)f2bf(lo) | ((unsigned)f2bf(hi) << 16);
}

// d_out: 33,554,432 f32 = Re(out[b,j]) at flat b*4096 + j.
// y1 intermediate: packed bf16 complex u32 (re|im<<16) at u32 slot b*4096 + r*64 + l.
// d_ws (>=2 MiB): fragment-ready bf16 weights (layouts unchanged since r10).

// ---------------------------------------------------------------------------
__global__ __launch_bounds__(256) void k_prep(const float* __restrict__ w1,
                                              const float* __restrict__ w2,
                                              unsigned int* __restrict__ w1f,
                                              unsigned int* __restrict__ w2f){
    const int g = blockIdx.x * 256 + threadIdx.x;
    if (g < 65536) {
        const int lane = g & 63, mw = (g >> 6) & 3, kc = (g >> 8) & 1, c = (g >> 9) & 1, r = g >> 10;
        const int Lrow = lane >> 4, idx = lane & 15;
        const float* src = w1 + ((size_t)(r * 64 + mw * 16 + idx) * 64 + kc * 32 + Lrow * 8) * 2 + c;
        unsigned o[4];
        #pragma unroll
        for (int jp = 0; jp < 4; ++jp)
            o[jp] = pack2(src[jp * 4], src[jp * 4 + 2]);
        *(u32x4*)(w1f + (size_t)g * 4) = *(u32x4*)o;
    } else {
        const int h = g - 65536;
        const int lane = h & 63, mw = (h >> 6) & 3, kc = (h >> 8) & 3, l = h >> 10;
        const int Lrow = lane >> 4, idx = lane & 15;
        const float* src = w2 + ((size_t)(l * 64 + mw * 16 + idx) * 64 + kc * 16 + Lrow * 4) * 2;
        unsigned o[4];
        #pragma unroll
        for (int jp = 0; jp < 4; ++jp)
            o[jp] = pack2(src[jp * 2], -src[jp * 2 + 1]);   // (re, -im)
        *(u32x4*)(w2f + (size_t)h * 4) = *(u32x4*)o;
    }
}

// ---------------------------------------------------------------------------
// Stage 1: y1[b, r*64+l] = sum_p w1[r,l,p] * x[b, p*64+r]
// Pair-swizzle decode (halves x HBM fetch) + 4-deep pipelined staging
// (compile-time-indexed arrays: 32 VGPR of staging state, no spill) +
// (256,2) bounds to allow the compiler a deeper schedule.
// ---------------------------------------------------------------------------
__global__ __launch_bounds__(256, 2) void k_stage1f(const float* __restrict__ x,
                                                    const unsigned short* __restrict__ w1b,
                                                    unsigned int* __restrict__ y1){
    __shared__ unsigned int BF[8192];              // 32 KB
    const int tid = threadIdx.x;
    const int bid = blockIdx.x;
    // pair swizzle: (bt, rc=2k) at bid B, (bt, rc=2k+1) at B+8 (same XCD, adjacent)
    const int inner = (bid >> 3) & 1;
    const int pp = (bid >> 4) * 8 + (bid & 7);
    const int bt = pp >> 1, rc = (pp & 1) * 2 + inner;
    const int b0 = bt * 16, r0 = rc * 16;

    {   // ---- stage x tile -> LDS, 4-deep software pipeline ----
        const int pe = tid >> 3;
        const int rq = (tid >> 1) & 3;
        const int bh = tid & 1;
        const int kc = pe >> 4, gg = (pe >> 2) & 3, jp = pe & 3;
        const float* src = x + (size_t)(b0 + bh * 8) * 4096 + (pe * 2) * 64 + r0 + rq * 4;

        f32x4 pa[4], pb[4];
        #pragma unroll
        for (int i = 0; i < 4; ++i) {
            pa[i] = *(const f32x4*)(src + (size_t)i * 4096);
            pb[i] = *(const f32x4*)(src + (size_t)i * 4096 + 64);
        }
        #pragma unroll
        for (int itr = 0; itr < 8; ++itr) {
            f32x4 v0 = pa[itr & 3];
            f32x4 v1 = pb[itr & 3];
            if (itr + 4 < 8) {
                pa[itr & 3] = *(const f32x4*)(src + (size_t)(itr + 4) * 4096);
                pb[itr & 3] = *(const f32x4*)(src + (size_t)(itr + 4) * 4096 + 64);
            }
            const int b = bh * 8 + itr;
            const int ROW = ((b ^ (b >> 3) ^ (gg << 1) ^ kc ^ (rq << 2)) & 15) | (gg << 4);
            const int base = kc * 256 + ROW * 4 + jp;
            #pragma unroll
            for (int m = 0; m < 4; ++m)
                BF[(rq * 4 + m) * 512 + base] = pack2(v0[m], v1[m]);
        }
    }
    __syncthreads();

    const int lane = tid & 63, mw = tid >> 6;
    const int Lrow = lane >> 4, idx = lane & 15;
    const unsigned short* wbase = w1b + mw * 512 + lane * 8;

    #pragma unroll
    for (int rr2 = 0; rr2 < 8; ++rr2) {
        const int rA = rr2 * 2;
        f32x4 acc[2][2] = {};
        #pragma unroll
        for (int kc = 0; kc < 2; ++kc) {
            const int ROWr = ((idx ^ (idx >> 3) ^ (Lrow << 1) ^ kc ^ ((rr2 >> 1) << 2)) & 15) | (Lrow << 4);
            short8 bA = *(const short8*)&BF[(rA + 0) * 512 + kc * 256 + ROWr * 4];
            short8 bB = *(const short8*)&BF[(rA + 1) * 512 + kc * 256 + ROWr * 4];
            #pragma unroll
            for (int rp = 0; rp < 2; ++rp) {
                const size_t wb = (size_t)(r0 + rA + rp) * 8192 + kc * 2048;
                short8 a0 = *(const short8*)(wbase + wb);          // re
                short8 a1 = *(const short8*)(wbase + wb + 4096);   // im
                short8 bb = rp ? bB : bA;
                acc[rp][0] = MFMA(a0, bb, acc[rp][0]);
                acc[rp][1] = MFMA(a1, bb, acc[rp][1]);
            }
        }
        #pragma unroll
        for (int rp = 0; rp < 2; ++rp) {
            u32x4 ov;
            #pragma unroll
            for (int reg = 0; reg < 4; ++reg)
                ov[reg] = pack2(acc[rp][0][reg], acc[rp][1][reg]);   // re | im<<16
            *(u32x4*)(y1 + (size_t)(b0 + idx) * 4096 + (size_t)(r0 + rA + rp) * 64 + mw * 16 + Lrow * 4) = ov;
        }
    }
}

// ---------------------------------------------------------------------------
// Stage 2 (real output only, in place over d_out) — r11 version (at its
// traffic floor; untouched).
// ---------------------------------------------------------------------------
__global__ __launch_bounds__(256) void k_stage2f(const unsigned int* __restrict__ y1,
                                                 const unsigned short* __restrict__ w2b,
                                                 float* __restrict__ outf){
    __shared__ unsigned int Y[16384];              // 64 KB
    const int tid = threadIdx.x;
    const int bid = blockIdx.x;
    const int inner = (bid >> 3) & 1;
    const int pp = (bid >> 4) * 8 + (bid & 7);
    const int bt = pp >> 1, lc = (pp & 1) * 2 + inner;
    const int b0 = bt * 16, l0 = lc * 16;
    const int lane = tid & 63, mw = tid >> 6;
    const int Lrow = lane >> 4, idx = lane & 15;

    {   // ---- stage y1 l-slice -> LDS (all global reads precede the barrier) ----
        const int r_lo = lane >> 2, cg = lane & 3;
        const int r = mw * 16 + r_lo;
        const unsigned int* src = y1 + (size_t)b0 * 4096 + r * 64 + l0 + cg * 4;
        #pragma unroll
        for (int b = 0; b < 16; ++b) {
            u32x4 v = *(const u32x4*)(src + (size_t)b * 4096);
            const int rsw = r ^ (b << 2) ^ ((cg & 1) << 4);
            #pragma unroll
            for (int q = 0; q < 4; ++q)
                Y[(cg * 4 + q) * 1024 + b * 64 + rsw] = v[q];
        }
    }
    __syncthreads();

    const unsigned short* wbase = w2b + mw * 512 + lane * 8;
    float vRe[4][16];
    #pragma unroll
    for (int li = 0; li < 16; ++li) {
        const int l = l0 + li;
        const int g1 = ((li >> 2) & 1) << 4;
        f32x4 aRe = {};
        #pragma unroll
        for (int kc = 0; kc < 4; ++kc) {
            const int rb = kc * 16 + Lrow * 4;
            const int rsw = rb ^ (idx << 2) ^ g1;
            short8 bfrag = *(const short8*)&Y[li * 1024 + idx * 64 + rsw];
            short8 are   = *(const short8*)(wbase + (size_t)l * 8192 + kc * 2048);
            aRe = MFMA(are, bfrag, aRe);
        }
        #pragma unroll
        for (int reg = 0; reg < 4; ++reg)
            vRe[reg][li] = aRe[reg];
    }

    __syncthreads();
    float* Yf = (float*)Y;
    #pragma unroll
    for (int reg = 0; reg < 4; ++reg) {
        const int s = mw * 16 + Lrow * 4 + reg;
        #pragma unroll
        for (int q = 0; q < 4; ++q) {
            f32x4 v = { vRe[reg][q*4+0], vRe[reg][q*4+1], vRe[reg][q*4+2], vRe[reg][q*4+3] };
            *(f32x4*)&Yf[idx * 1024 + s * 16 + (((q ^ (idx & 3)) << 2))] = v;
        }
    }
    __syncthreads();

    {   // ---- coalesced store ----
        const int s2 = tid >> 2, c4 = tid & 3;
        #pragma unroll
        for (int i = 0; i < 16; ++i) {
            f32x4 v = *(const f32x4*)&Yf[i * 1024 + s2 * 16 + (((c4 ^ (i & 3)) << 2))];
            *(f32x4*)(outf + (size_t)(b0 + i) * 4096 + s2 * 64 + l0 + c4 * 4) = v;
        }
    }
}

// ===========================================================================
// Fallback path (round-9 verified kernels) — used only if ws_size < 2 MiB.
// ===========================================================================
__global__ __launch_bounds__(256) void k_stage1(const float* __restrict__ x,
                                                const float* __restrict__ w1,
                                                unsigned int* __restrict__ y1){
    __shared__ unsigned int BF[8192];
    const int tid = threadIdx.x;
    const int bt = blockIdx.x >> 2, rc = blockIdx.x & 3;
    const int b0 = bt * 16, r0 = rc * 16;
    {
        const int pe = tid >> 3;
        const int rq = (tid >> 1) & 3;
        const int bh = tid & 1;
        const int kc = pe >> 4, gg = (pe >> 2) & 3, jp = pe & 3;
        const float* src = x + (size_t)(b0 + bh * 8) * 4096 + (pe * 2) * 64 + r0 + rq * 4;
        #pragma unroll
        for (int itr = 0; itr < 8; ++itr) {
            f32x4 v0 = *(const f32x4*)(src + (size_t)itr * 4096);
            f32x4 v1 = *(const f32x4*)(src + (size_t)itr * 4096 + 64);
            const int b = bh * 8 + itr;
            const int ROW = ((b ^ (b >> 3) ^ (gg << 1) ^ kc ^ (rq << 2)) & 15) | (gg << 4);
            const int base = kc * 256 + ROW * 4 + jp;
            #pragma unroll
            for (int m = 0; m < 4; ++m)
                BF[(rq * 4 + m) * 512 + base] = pack2(v0[m], v1[m]);
        }
    }
    __syncthreads();
    const int lane = tid & 63, mw = tid >> 6;
    const int Lrow = lane >> 4, idx = lane & 15;
    #pragma unroll
    for (int rr2 = 0; rr2 < 8; ++rr2) {
        const int rA = rr2 * 2;
        f32x4 acc[2][2] = {};
        #pragma unroll
        for (int kc = 0; kc < 2; ++kc) {
            const int ROWr = ((idx ^ (idx >> 3) ^ (Lrow << 1) ^ kc ^ ((rr2 >> 1) << 2)) & 15) | (Lrow << 4);
            short8 bA = *(const short8*)&BF[(rA + 0) * 512 + kc * 256 + ROWr * 4];
            short8 bB = *(const short8*)&BF[(rA + 1) * 512 + kc * 256 + ROWr * 4];
            #pragma unroll
            for (int rp = 0; rp < 2; ++rp) {
                const int r = r0 + rA + rp;
                const float* wp = w1 + (((size_t)r * 64 + mw * 16 + idx) * 64 + kc * 32 + Lrow * 8) * 2;
                f32x4 q0 = *(const f32x4*)(wp);
                f32x4 q1 = *(const f32x4*)(wp + 4);
                f32x4 q2 = *(const f32x4*)(wp + 8);
                f32x4 q3 = *(const f32x4*)(wp + 12);
                short8 a0, a1;
                unsigned* p0 = (unsigned*)&a0; unsigned* p1 = (unsigned*)&a1;
                p0[0] = pack2(q0[0], q0[2]); p0[1] = pack2(q1[0], q1[2]);
                p0[2] = pack2(q2[0], q2[2]); p0[3] = pack2(q3[0], q3[2]);
                p1[0] = pack2(q0[1], q0[3]); p1[1] = pack2(q1[1], q1[3]);
                p1[2] = pack2(q2[1], q2[3]); p1[3] = pack2(q3[1], q3[3]);
                short8 bb = rp ? bB : bA;
                acc[rp][0] = MFMA(a0, bb, acc[rp][0]);
                acc[rp][1] = MFMA(a1, bb, acc[rp][1]);
            }
        }
        #pragma unroll
        for (int rp = 0; rp < 2; ++rp) {
            u32x4 ov;
            #pragma unroll
            for (int reg = 0; reg < 4; ++reg)
                ov[reg] = pack2(acc[rp][0][reg], acc[rp][1][reg]);
            *(u32x4*)(y1 + (size_t)(b0 + idx) * 4096 + (size_t)(r0 + rA + rp) * 64 + mw * 16 + Lrow * 4) = ov;
        }
    }
}

__global__ __launch_bounds__(256) void k_stage2(const unsigned int* __restrict__ y1,
                                                const float* __restrict__ w2,
                                                float* __restrict__ outf){
    __shared__ unsigned int Y[16384];
    const int tid = threadIdx.x;
    const int bt = blockIdx.x >> 2, lc = blockIdx.x & 3;
    const int b0 = bt * 16, l0 = lc * 16;
    const int lane = tid & 63, mw = tid >> 6;
    const int Lrow = lane >> 4, idx = lane & 15;
    {
        const int r_lo = lane >> 2, cg = lane & 3;
        const int r = mw * 16 + r_lo;
        const unsigned int* src = y1 + (size_t)b0 * 4096 + r * 64 + l0 + cg * 4;
        #pragma unroll
        for (int b = 0; b < 16; ++b) {
            u32x4 v = *(const u32x4*)(src + (size_t)b * 4096);
            const int rsw = r ^ (b << 2) ^ ((cg & 1) << 4);
            #pragma unroll
            for (int q = 0; q < 4; ++q)
                Y[(cg * 4 + q) * 1024 + b * 64 + rsw] = v[q];
        }
    }
    __syncthreads();
    float vRe[4][16];
    #pragma unroll
    for (int li = 0; li < 16; ++li) {
        const int l = l0 + li;
        const float* wp0 = w2 + ((size_t)l * 64 + mw * 16 + idx) * 128;
        const int g1 = ((li >> 2) & 1) << 4;
        f32x4 aRe = {};
        #pragma unroll
        for (int kc = 0; kc < 4; ++kc) {
            const int rb = kc * 16 + Lrow * 4;
            const int rsw = rb ^ (idx << 2) ^ g1;
            short8 bfrag = *(const short8*)&Y[li * 1024 + idx * 64 + rsw];
            const float* wp = wp0 + rb * 2;
            f32x4 u  = *(const f32x4*)wp;
            f32x4 vv = *(const f32x4*)(wp + 4);
            short8 are;
            unsigned* pr = (unsigned*)&are;
            pr[0] = pack2(u[0], -u[1]);   pr[1] = pack2(u[2], -u[3]);
            pr[2] = pack2(vv[0], -vv[1]); pr[3] = pack2(vv[2], -vv[3]);
            aRe = MFMA(are, bfrag, aRe);
        }
        #pragma unroll
        for (int reg = 0; reg < 4; ++reg)
            vRe[reg][li] = aRe[reg];
    }
    #pragma unroll
    for (int reg = 0; reg < 4; ++reg) {
        float* dst = outf + (size_t)(b0 + idx) * 4096 + (size_t)(mw * 16 + Lrow * 4 + reg) * 64 + l0;
        #pragma unroll
        for (int h = 0; h < 4; ++h) {
            f32x4 wv;
            wv[0] = vRe[reg][h*4+0]; wv[1] = vRe[reg][h*4+1];
            wv[2] = vRe[reg][h*4+2]; wv[3] = vRe[reg][h*4+3];
            *(f32x4*)(dst + h * 4) = wv;
        }
    }
}

extern "C" void kernel_launch(void* const* d_in, const int* in_sizes, int n_in,
                              void* d_out, int out_size, void* d_ws, size_t ws_size,
                              hipStream_t stream) {
    const float* x  = (const float*)d_in[0];
    const float* w1 = (const float*)d_in[1];
    const float* w2 = (const float*)d_in[2];
    unsigned int* y1 = (unsigned int*)d_out;
    float* outf = (float*)d_out;

    if (ws_size >= (size_t)2 * 1024 * 1024) {
        unsigned int* w1f = (unsigned int*)d_ws;           // 1 MiB
        unsigned int* w2f = w1f + 262144;                  // 1 MiB
        k_prep   <<<dim3(512),  dim3(256), 0, stream>>>(w1, w2, w1f, w2f);
        k_stage1f<<<dim3(2048), dim3(256), 0, stream>>>(x, (const unsigned short*)w1f, y1);
        k_stage2f<<<dim3(2048), dim3(256), 0, stream>>>(y1, (const unsigned short*)w2f, outf);
    } else {
        k_stage1<<<dim3(2048), dim3(256), 0, stream>>>(x, w1, y1);
        k_stage2<<<dim3(2048), dim3(256), 0, stream>>>(y1, w2, outf);
    }
}